// Round 5
// baseline (320.345 us; speedup 1.0000x reference)
//
#include <hip/hip_runtime.h>
#include <math.h>

typedef __bf16 bf16_t;
typedef __bf16 bf16x4 __attribute__((ext_vector_type(4)));
typedef __bf16 bf16x8 __attribute__((ext_vector_type(8)));
typedef float floatx4 __attribute__((ext_vector_type(4)));

#define MFMA16(A, B, C) __builtin_amdgcn_mfma_f32_16x16x32_bf16((A), (B), (C), 0, 0, 0)

static constexpr int BB  = 2;
static constexpr int NH  = 12;
static constexpr int HD  = 64;
static constexpr int DIM = 768;    // NH*HD
static constexpr int QS  = 1568;   // 8*14*14
static constexpr int KS  = 1568;
static constexpr int KSP = 1600;   // padded key stride for vT (OOB reads hit pad)
static constexpr int MROWS = BB * QS;  // 3136
static constexpr int KT  = 112;    // attention K-tile (1568 = 14*112)

// async global->LDS, 16B per lane (LDS dest must be wave-uniform base + lane*16)
__device__ __forceinline__ void async16(const void* g, void* l) {
    __builtin_amdgcn_global_load_lds(
        (const __attribute__((address_space(1))) unsigned int*)g,
        (__attribute__((address_space(3))) unsigned int*)l, 16, 0, 0);
}

// ---------------------------------------------------------------------------
// Convert the 4 weight matrices f32 -> bf16
// ---------------------------------------------------------------------------
__global__ __launch_bounds__(256) void cvt_w(
    const float* __restrict__ wq, const float* __restrict__ wk,
    const float* __restrict__ wv, const float* __restrict__ wo,
    bf16_t* __restrict__ Wb)
{
    const int NW = DIM * DIM / 4;   // 147456 float4 per matrix
    int i = blockIdx.x * 256 + threadIdx.x;
    if (i >= 4 * NW) return;
    const int w = i / NW;
    const int off = i - w * NW;
    const float* src = (w == 0) ? wq : (w == 1) ? wk : (w == 2) ? wv : wo;
    floatx4 v = ((const floatx4*)src)[off];
    bf16x4 o;
#pragma unroll
    for (int r = 0; r < 4; ++r) o[r] = (bf16_t)v[r];
    ((bf16x4*)(Wb + (size_t)w * DIM * DIM))[off] = o;
}

// ---------------------------------------------------------------------------
// Fused Q/K/V projection GEMM: Y = X @ W^T + b.
// grid (25, 36): blockIdx.y -> proj = y/12 (0:Q 1:K 2:V), n-block = y%12.
// X is f32 input (q or k), staged to LDS via async16 with XOR column swizzle.
// Tile 128M x 64N, BK=64. Outputs per-head layouts:
//   proj 0/1: dst[((bb*NH+head)*QS + key)*64 + cl]   (row-contiguous per head)
//   proj 2  : vT[((bb*NH+head)*64 + cl)*KSP + key]   (transposed, padded)
// ---------------------------------------------------------------------------
__global__ __launch_bounds__(256) void gemm_qkv(
    const float* __restrict__ q, const float* __restrict__ k,
    const bf16_t* __restrict__ Wb,
    const float* __restrict__ bq, const float* __restrict__ bk,
    const float* __restrict__ bv,
    bf16_t* __restrict__ qhP, bf16_t* __restrict__ khP, bf16_t* __restrict__ vT)
{
    __shared__ __align__(16) float  As[128 * 64];  // 32 KB (f32 staging)
    __shared__ __align__(16) bf16_t Bs[64 * 64];   // 8 KB

    const int tid   = threadIdx.x;
    const int lane  = tid & 63;
    const int wave  = tid >> 6;
    const int row16 = lane & 15;
    const int quad  = lane >> 4;
    const int wm    = wave & 1;
    const int wn    = wave >> 1;
    const int m0 = blockIdx.x * 128;
    const int yb = blockIdx.y;
    const int proj = yb / 12;
    const int n0 = (yb - proj * 12) * 64;

    const float* X = (proj == 0) ? q : k;
    const bf16_t* W = Wb + (size_t)proj * DIM * DIM;
    const float* bias = (proj == 0) ? bq : (proj == 1) ? bk : bv;

    floatx4 acc[4][2];
#pragma unroll
    for (int mt = 0; mt < 4; ++mt)
#pragma unroll
        for (int nt = 0; nt < 2; ++nt) acc[mt][nt] = (floatx4){0.f, 0.f, 0.f, 0.f};

    for (int k0 = 0; k0 < DIM; k0 += 64) {
        __syncthreads();
        // A: 128 rows x 16 groups of 4 f32; physical group p holds logical g=p^ (row&15)
#pragma unroll
        for (int pp = 0; pp < 8; ++pp) {
            const int c = pp * 256 + tid;
            const int row = c >> 4;
            const int g = (c & 15) ^ (row & 15);
            const int rowc = min(m0 + row, MROWS - 1);
            async16(X + (size_t)rowc * DIM + k0 + g * 4, As + c * 4);
        }
        // B: 64 rows x 8 groups of 8 bf16; physical p holds logical g=p^(row&7)
#pragma unroll
        for (int pp = 0; pp < 2; ++pp) {
            const int c = pp * 256 + tid;
            const int row = c >> 3;
            const int g = (c & 7) ^ (row & 7);
            async16(W + (size_t)(n0 + row) * DIM + k0 + g * 8, Bs + c * 8);
        }
        __syncthreads();

#pragma unroll
        for (int h = 0; h < 2; ++h) {
            bf16x8 aF[4], bF[2];
            const int g0 = h * 8 + quad * 2;
#pragma unroll
            for (int mt = 0; mt < 4; ++mt) {
                const int rowA = wm * 64 + mt * 16 + row16;
                floatx4 lo = *(const floatx4*)&As[rowA * 64 + (g0 ^ row16) * 4];
                floatx4 hi = *(const floatx4*)&As[rowA * 64 + ((g0 + 1) ^ row16) * 4];
                bf16x8 a;
#pragma unroll
                for (int j = 0; j < 4; ++j) { a[j] = (bf16_t)lo[j]; a[4 + j] = (bf16_t)hi[j]; }
                aF[mt] = a;
            }
            const int gl = h * 4 + quad;
#pragma unroll
            for (int nt = 0; nt < 2; ++nt) {
                const int rowB = wn * 32 + nt * 16 + row16;
                bF[nt] = *(const bf16x8*)&Bs[rowB * 64 + (gl ^ (row16 & 7)) * 8];
            }
#pragma unroll
            for (int mt = 0; mt < 4; ++mt)
#pragma unroll
                for (int nt = 0; nt < 2; ++nt)
                    acc[mt][nt] = MFMA16(aF[mt], bF[nt], acc[mt][nt]);
        }
    }

#pragma unroll
    for (int nt = 0; nt < 2; ++nt) {
        const int col = n0 + wn * 32 + nt * 16 + row16;
        const int head = col >> 6, cl = col & 63;
        const float bv_ = bias[col];
#pragma unroll
        for (int mt = 0; mt < 4; ++mt) {
            const int row0 = m0 + wm * 64 + mt * 16 + quad * 4;
            if (row0 < MROWS) {
                const int bb = (row0 >= KS) ? 1 : 0;
                const int key0 = row0 - bb * KS;
                if (proj == 2) {
                    bf16x4 pv;
#pragma unroll
                    for (int r = 0; r < 4; ++r) pv[r] = (bf16_t)(acc[mt][nt][r] + bv_);
                    *(bf16x4*)&vT[((size_t)(bb * NH + head) * 64 + cl) * KSP + key0] = pv;
                } else {
                    bf16_t* dst = (proj == 0) ? qhP : khP;
#pragma unroll
                    for (int r = 0; r < 4; ++r)
                        dst[((size_t)(bb * NH + head) * KS + key0 + r) * 64 + cl] =
                            (bf16_t)(acc[mt][nt][r] + bv_);
                }
            }
        }
    }
}

// ---------------------------------------------------------------------------
// Fused flash attention, barrier-free K-loop. Block = 128 thr / 2 waves per
// (b, n, 32 q-rows); grid 1176, XCD-swizzled so each (b,n) stays on one XCD.
// K/V fragments loaded directly from per-head global layouts (L2-served).
// Only LDS in the loop: per-wave P C->A layout round-trip (lgkm-ordered).
// ---------------------------------------------------------------------------
__global__ __launch_bounds__(128) void attn_fused(
    const bf16_t* __restrict__ qhP, const bf16_t* __restrict__ khP,
    const bf16_t* __restrict__ vT,
    const float* __restrict__ rpt, const float* __restrict__ rph,
    const float* __restrict__ rpw, bf16_t* __restrict__ ao)
{
    __shared__ float  relS[36 * 36];     // [e][36]: 32 q-rows + pad
    __shared__ bf16_t Pl[2 * 16 * 136];  // per-wave [16][136]; keys 112.. stay 0

    const int tid   = threadIdx.x;
    const int lane  = tid & 63;
    const int wave  = tid >> 6;
    const int row16 = lane & 15;
    const int quad  = lane >> 4;

    // XCD swizzle: all 49 q-blocks of one (b,n) share blockIdx%8
    const int L = blockIdx.x;           // 0..1175  (= 8 * 3 * 49)
    const int xcd = L & 7;
    const int j = L >> 3;
    const int bn = xcd * 3 + (j % 3);   // 0..23
    const int q0 = (j / 3) * 32;
    const int b = bn / NH;
    const int n = bn - b * NH;

    const float LOG2E = 1.4426950408889634f;
    const float SCALE_L2E = 0.125f * LOG2E;

    // zero Pl (incl. the key-pad region read by the c4=3 aP fragment)
    for (int i = tid; i < 2 * 16 * 136 / 2; i += 128) ((int*)Pl)[i] = 0;

    // prologue: relS[e][ql] = LOG2E * (qh[q0+ql] . table_e), 36 x 32 entries
    for (int i = tid; i < 36 * 32; i += 128) {
        const int e  = i >> 5;
        const int ql = i & 31;
        const int qg = q0 + ql;
        const float* tp;
        if (e < 8)       { int tq = qg / 196;       tp = rpt + (size_t)(tq - e + 7) * HD; }
        else if (e < 22) { int hq = (qg / 14) % 14; tp = rph + (size_t)(hq - (e - 8) + 13) * HD; }
        else             { int wq = qg % 14;        tp = rpw + (size_t)(wq - (e - 22) + 13) * HD; }
        const bf16_t* qp = qhP + ((size_t)bn * QS + qg) * 64;
        float s = 0.f;
#pragma unroll
        for (int jj = 0; jj < 8; ++jj) {
            bf16x8 a = *(const bf16x8*)(qp + jj * 8);
            floatx4 t0 = *(const floatx4*)(tp + jj * 8);
            floatx4 t1 = *(const floatx4*)(tp + jj * 8 + 4);
#pragma unroll
            for (int r = 0; r < 4; ++r) s += (float)a[r] * t0[r];
#pragma unroll
            for (int r = 0; r < 4; ++r) s += (float)a[4 + r] * t1[r];
        }
        relS[e * 36 + ql] = s * LOG2E;
    }

    // persistent Q fragments (A-layout)
    const int qrow = q0 + wave * 16 + row16;
    const bf16_t* qp = qhP + ((size_t)bn * QS + qrow) * 64 + quad * 8;
    bf16x8 aQ0 = *(const bf16x8*)(qp);
    bf16x8 aQ1 = *(const bf16x8*)(qp + 32);

    floatx4 O[4];
#pragma unroll
    for (int ct = 0; ct < 4; ++ct) O[ct] = (floatx4){0.f, 0.f, 0.f, 0.f};
    float lsum[4] = {0.f, 0.f, 0.f, 0.f};

    const bf16_t* khb = khP + (size_t)bn * KS * 64;
    const bf16_t* vTb = vT + (size_t)bn * 64 * KSP;
    const int rowb  = wave * 16 + quad * 4;  // local q-row base (0..28)
    const int pbase = (wave * 16) * 136;

    __syncthreads();  // relS + Pl zeros visible

    for (int k0 = 0; k0 < KS; k0 += KT) {
        // ---- V fragments (B-operand), issued early; keys 112..127 read pad
        bf16x8 vF[16];
#pragma unroll
        for (int ct = 0; ct < 4; ++ct)
#pragma unroll
            for (int c4 = 0; c4 < 4; ++c4)
                vF[ct * 4 + c4] = *(const bf16x8*)(
                    vTb + (size_t)(ct * 16 + row16) * KSP + k0 + c4 * 32 + quad * 8);

        // ---- S = Q K^T: 7 tiles of 16 keys, K-frags direct (128B rows)
        floatx4 S[7];
#pragma unroll
        for (int t = 0; t < 7; ++t) {
            const bf16_t* kp = khb + (size_t)(k0 + t * 16 + row16) * 64 + quad * 8;
            floatx4 s = (floatx4){0.f, 0.f, 0.f, 0.f};
            s = MFMA16(aQ0, *(const bf16x8*)(kp), s);
            s = MFMA16(aQ1, *(const bf16x8*)(kp + 32), s);
            S[t] = s;
        }

        // ---- bias + exp2 + P store + l accumulate
#pragma unroll
        for (int t = 0; t < 7; ++t) {
            const int key = k0 + t * 16 + row16;
            const int kt = key / 196;
            const int rem = key - kt * 196;
            const int kho = rem / 14;
            const int kwo = rem - kho * 14;
            floatx4 bias = *(const floatx4*)&relS[kt * 36 + rowb];
            bias = bias + *(const floatx4*)&relS[(8 + kho) * 36 + rowb];
            bias = bias + *(const floatx4*)&relS[(22 + kwo) * 36 + rowb];
#pragma unroll
            for (int r = 0; r < 4; ++r) {
                const float p = __builtin_amdgcn_exp2f(S[t][r] * SCALE_L2E + bias[r]);
                lsum[r] += p;
                Pl[pbase + (quad * 4 + r) * 136 + t * 16 + row16] = (bf16_t)p;
            }
        }

        // ---- O += P V (P via per-wave LDS round-trip; no barrier needed)
        bf16x8 aP[4];
#pragma unroll
        for (int c4 = 0; c4 < 4; ++c4)
            aP[c4] = *(const bf16x8*)&Pl[pbase + row16 * 136 + c4 * 32 + quad * 8];
#pragma unroll
        for (int ct = 0; ct < 4; ++ct) {
            floatx4 o = O[ct];
#pragma unroll
            for (int c4 = 0; c4 < 4; ++c4)
                o = MFMA16(aP[c4], vF[ct * 4 + c4], o);
            O[ct] = o;
        }
    }

    // ---- epilogue: reduce l across the 16-lane key group, normalize, store
    float inv[4];
#pragma unroll
    for (int r = 0; r < 4; ++r) {
        float l = lsum[r];
        l += __shfl_xor(l, 1);
        l += __shfl_xor(l, 2);
        l += __shfl_xor(l, 4);
        l += __shfl_xor(l, 8);
        inv[r] = 1.f / l;
    }
#pragma unroll
    for (int ct = 0; ct < 4; ++ct) {
        const int c = n * HD + ct * 16 + row16;
#pragma unroll
        for (int r = 0; r < 4; ++r) {
            const int qr = q0 + wave * 16 + quad * 4 + r;
            ao[(size_t)(b * QS + qr) * DIM + c] = (bf16_t)(O[ct][r] * inv[r]);
        }
    }
}

// ---------------------------------------------------------------------------
// O-projection GEMM: Y(f32) = X(bf16) @ Wo^T + bo. Tile 64x64, BK=64,
// grid (49, 12) = 588 blocks (no M padding needed). XOR-swizzled LDS.
// ---------------------------------------------------------------------------
__global__ __launch_bounds__(256) void gemm_o(
    const bf16_t* __restrict__ X, const bf16_t* __restrict__ W,
    const float* __restrict__ bias, float* __restrict__ Y)
{
    __shared__ __align__(16) bf16_t As[64 * 64];   // 8 KB
    __shared__ __align__(16) bf16_t Bs[64 * 64];   // 8 KB

    const int tid   = threadIdx.x;
    const int lane  = tid & 63;
    const int wave  = tid >> 6;
    const int row16 = lane & 15;
    const int quad  = lane >> 4;
    const int m0 = blockIdx.x * 64;
    const int n0 = blockIdx.y * 64;

    floatx4 acc[4];
#pragma unroll
    for (int nt = 0; nt < 4; ++nt) acc[nt] = (floatx4){0.f, 0.f, 0.f, 0.f};

    for (int k0 = 0; k0 < DIM; k0 += 64) {
        __syncthreads();
#pragma unroll
        for (int pp = 0; pp < 2; ++pp) {
            const int c = pp * 256 + tid;
            const int row = c >> 3;
            const int g = (c & 7) ^ (row & 7);
            async16(X + (size_t)(m0 + row) * DIM + k0 + g * 8, As + c * 8);
            async16(W + (size_t)(n0 + row) * DIM + k0 + g * 8, Bs + c * 8);
        }
        __syncthreads();

#pragma unroll
        for (int h = 0; h < 2; ++h) {
            const int gl = h * 4 + quad;
            const int rowA = wave * 16 + row16;
            bf16x8 aF = *(const bf16x8*)&As[rowA * 64 + (gl ^ (row16 & 7)) * 8];
#pragma unroll
            for (int nt = 0; nt < 4; ++nt) {
                const int rowB = nt * 16 + row16;
                bf16x8 bF = *(const bf16x8*)&Bs[rowB * 64 + (gl ^ (row16 & 7)) * 8];
                acc[nt] = MFMA16(aF, bF, acc[nt]);
            }
        }
    }

#pragma unroll
    for (int nt = 0; nt < 4; ++nt) {
        const int col = n0 + nt * 16 + row16;
        const float bv = bias[col];
#pragma unroll
        for (int r = 0; r < 4; ++r) {
            const int row = m0 + wave * 16 + quad * 4 + r;
            Y[(size_t)row * DIM + col] = acc[nt][r] + bv;
        }
    }
}

// ---------------------------------------------------------------------------
extern "C" void kernel_launch(void* const* d_in, const int* in_sizes, int n_in,
                              void* d_out, int out_size, void* d_ws, size_t ws_size,
                              hipStream_t stream) {
    const float* q   = (const float*)d_in[0];
    const float* k   = (const float*)d_in[1];
    const float* Wq  = (const float*)d_in[2];
    const float* bq  = (const float*)d_in[3];
    const float* Wk  = (const float*)d_in[4];
    const float* bk  = (const float*)d_in[5];
    const float* Wv  = (const float*)d_in[6];
    const float* bv  = (const float*)d_in[7];
    const float* Wo  = (const float*)d_in[8];
    const float* bo  = (const float*)d_in[9];
    const float* rpt = (const float*)d_in[10];
    const float* rph = (const float*)d_in[11];
    const float* rpw = (const float*)d_in[12];

    // workspace (bf16): qhP, khP (MROWS*64-per-head = MROWS*DIM), vT (padded),
    // ao, Wb  -> total ~24.1 MB
    bf16_t* qhP = (bf16_t*)d_ws;
    bf16_t* khP = qhP + (size_t)MROWS * DIM;
    bf16_t* vT  = khP + (size_t)MROWS * DIM;
    bf16_t* ao  = vT  + (size_t)BB * NH * HD * KSP;
    bf16_t* Wb  = ao  + (size_t)MROWS * DIM;      // [Wq|Wk|Wv|Wo]

    cvt_w<<<(4 * (DIM * DIM / 4) + 255) / 256, 256, 0, stream>>>(Wq, Wk, Wv, Wo, Wb);

    gemm_qkv<<<dim3(25, 36), 256, 0, stream>>>(q, k, Wb, bq, bk, bv, qhP, khP, vT);

    attn_fused<<<dim3(8 * 3 * 49), 128, 0, stream>>>(
        qhP, khP, vT, rpt, rph, rpw, ao);

    gemm_o<<<dim3(MROWS / 64, DIM / 64), 256, 0, stream>>>(
        ao, Wb + (size_t)3 * DIM * DIM, bo, (float*)d_out);
}

// Round 6
// 277.065 us; speedup vs baseline: 1.1562x; 1.1562x over previous
//
#include <hip/hip_runtime.h>
#include <math.h>

typedef __bf16 bf16_t;
typedef __bf16 bf16x4 __attribute__((ext_vector_type(4)));
typedef __bf16 bf16x8 __attribute__((ext_vector_type(8)));
typedef float floatx4 __attribute__((ext_vector_type(4)));

#define MFMA16(A, B, C) __builtin_amdgcn_mfma_f32_16x16x32_bf16((A), (B), (C), 0, 0, 0)

static constexpr int BB  = 2;
static constexpr int NH  = 12;
static constexpr int HD  = 64;
static constexpr int DIM = 768;    // NH*HD
static constexpr int QS  = 1568;   // 8*14*14
static constexpr int KS  = 1568;
static constexpr int KSP = 1664;   // padded key stride for vT (13*128)
static constexpr int MROWS = BB * QS;  // 3136
static constexpr int KT  = 128;    // attention K-tile; 13 iters, last masked

// async global->LDS, 16B per lane (LDS dest must be wave-uniform base + lane*16)
__device__ __forceinline__ void async16(const void* g, void* l) {
    __builtin_amdgcn_global_load_lds(
        (const __attribute__((address_space(1))) unsigned int*)g,
        (__attribute__((address_space(3))) unsigned int*)l, 16, 0, 0);
}

// ---------------------------------------------------------------------------
// Convert the 4 weight matrices f32 -> bf16
// ---------------------------------------------------------------------------
__global__ __launch_bounds__(256) void cvt_w(
    const float* __restrict__ wq, const float* __restrict__ wk,
    const float* __restrict__ wv, const float* __restrict__ wo,
    bf16_t* __restrict__ Wb)
{
    const int NW = DIM * DIM / 4;   // 147456 float4 per matrix
    int i = blockIdx.x * 256 + threadIdx.x;
    if (i >= 4 * NW) return;
    const int w = i / NW;
    const int off = i - w * NW;
    const float* src = (w == 0) ? wq : (w == 1) ? wk : (w == 2) ? wv : wo;
    floatx4 v = ((const floatx4*)src)[off];
    bf16x4 o;
#pragma unroll
    for (int r = 0; r < 4; ++r) o[r] = (bf16_t)v[r];
    ((bf16x4*)(Wb + (size_t)w * DIM * DIM))[off] = o;
}

// ---------------------------------------------------------------------------
// Fused Q/K/V projection GEMM: Y = X @ W^T + b.
// grid (25, 36): blockIdx.y -> proj = y/12 (0:Q 1:K 2:V), n-block = y%12.
// Outputs per-head layouts:
//   proj 0/1: dst[((bb*NH+head)*QS + key)*64 + cl]
//   proj 2  : vT[((bb*NH+head)*64 + cl)*KSP + key]   (transposed, padded)
// ---------------------------------------------------------------------------
__global__ __launch_bounds__(256) void gemm_qkv(
    const float* __restrict__ q, const float* __restrict__ k,
    const bf16_t* __restrict__ Wb,
    const float* __restrict__ bq, const float* __restrict__ bk,
    const float* __restrict__ bv,
    bf16_t* __restrict__ qhP, bf16_t* __restrict__ khP, bf16_t* __restrict__ vT)
{
    __shared__ __align__(16) float  As[128 * 64];  // 32 KB (f32 staging)
    __shared__ __align__(16) bf16_t Bs[64 * 64];   // 8 KB

    const int tid   = threadIdx.x;
    const int lane  = tid & 63;
    const int wave  = tid >> 6;
    const int row16 = lane & 15;
    const int quad  = lane >> 4;
    const int wm    = wave & 1;
    const int wn    = wave >> 1;
    const int m0 = blockIdx.x * 128;
    const int yb = blockIdx.y;
    const int proj = yb / 12;
    const int n0 = (yb - proj * 12) * 64;

    const float* X = (proj == 0) ? q : k;
    const bf16_t* W = Wb + (size_t)proj * DIM * DIM;
    const float* bias = (proj == 0) ? bq : (proj == 1) ? bk : bv;

    floatx4 acc[4][2];
#pragma unroll
    for (int mt = 0; mt < 4; ++mt)
#pragma unroll
        for (int nt = 0; nt < 2; ++nt) acc[mt][nt] = (floatx4){0.f, 0.f, 0.f, 0.f};

    for (int k0 = 0; k0 < DIM; k0 += 64) {
        __syncthreads();
#pragma unroll
        for (int pp = 0; pp < 8; ++pp) {
            const int c = pp * 256 + tid;
            const int row = c >> 4;
            const int g = (c & 15) ^ (row & 15);
            const int rowc = min(m0 + row, MROWS - 1);
            async16(X + (size_t)rowc * DIM + k0 + g * 4, As + c * 4);
        }
#pragma unroll
        for (int pp = 0; pp < 2; ++pp) {
            const int c = pp * 256 + tid;
            const int row = c >> 3;
            const int g = (c & 7) ^ (row & 7);
            async16(W + (size_t)(n0 + row) * DIM + k0 + g * 8, Bs + c * 8);
        }
        __syncthreads();

#pragma unroll
        for (int h = 0; h < 2; ++h) {
            bf16x8 aF[4], bF[2];
            const int g0 = h * 8 + quad * 2;
#pragma unroll
            for (int mt = 0; mt < 4; ++mt) {
                const int rowA = wm * 64 + mt * 16 + row16;
                floatx4 lo = *(const floatx4*)&As[rowA * 64 + (g0 ^ row16) * 4];
                floatx4 hi = *(const floatx4*)&As[rowA * 64 + ((g0 + 1) ^ row16) * 4];
                bf16x8 a;
#pragma unroll
                for (int j = 0; j < 4; ++j) { a[j] = (bf16_t)lo[j]; a[4 + j] = (bf16_t)hi[j]; }
                aF[mt] = a;
            }
            const int gl = h * 4 + quad;
#pragma unroll
            for (int nt = 0; nt < 2; ++nt) {
                const int rowB = wn * 32 + nt * 16 + row16;
                bF[nt] = *(const bf16x8*)&Bs[rowB * 64 + (gl ^ (row16 & 7)) * 8];
            }
#pragma unroll
            for (int mt = 0; mt < 4; ++mt)
#pragma unroll
                for (int nt = 0; nt < 2; ++nt)
                    acc[mt][nt] = MFMA16(aF[mt], bF[nt], acc[mt][nt]);
        }
    }

#pragma unroll
    for (int nt = 0; nt < 2; ++nt) {
        const int col = n0 + wn * 32 + nt * 16 + row16;
        const int head = col >> 6, cl = col & 63;
        const float bv_ = bias[col];
#pragma unroll
        for (int mt = 0; mt < 4; ++mt) {
            const int row0 = m0 + wm * 64 + mt * 16 + quad * 4;
            if (row0 < MROWS) {
                const int bb = (row0 >= KS) ? 1 : 0;
                const int key0 = row0 - bb * KS;
                if (proj == 2) {
                    bf16x4 pv;
#pragma unroll
                    for (int r = 0; r < 4; ++r) pv[r] = (bf16_t)(acc[mt][nt][r] + bv_);
                    *(bf16x4*)&vT[((size_t)(bb * NH + head) * 64 + cl) * KSP + key0] = pv;
                } else {
                    bf16_t* dst = (proj == 0) ? qhP : khP;
#pragma unroll
                    for (int r = 0; r < 4; ++r)
                        dst[((size_t)(bb * NH + head) * KS + key0 + r) * 64 + cl] =
                            (bf16_t)(acc[mt][nt][r] + bv_);
                }
            }
        }
    }
}

// ---------------------------------------------------------------------------
// Fused flash attention (m97-style staged K-loop).
// Block: 256 thr / 4 waves; q-tile 64 (wave = 16 q-rows); K-tile 128, 13 iters.
// K staged to LDS (stride 80: 2-way writes / 4-way frag reads).
// V fragments direct from global vT, issued at iter top, consumed at bottom.
// Softmax: no running max (scores bounded); tail keys masked to p=0.
// ---------------------------------------------------------------------------
__global__ __launch_bounds__(256) void attn_fused(
    const bf16_t* __restrict__ qhP, const bf16_t* __restrict__ khP,
    const bf16_t* __restrict__ vT,
    const float* __restrict__ rpt, const float* __restrict__ rph,
    const float* __restrict__ rpw, bf16_t* __restrict__ ao)
{
    __shared__ __align__(16) bf16_t Ks[128 * 80];   // 20480 B, padded stride
    __shared__ __align__(16) float  relS[36 * 68];  // 9792 B
    __shared__ __align__(16) bf16_t Pl[4 * 16 * 136]; // 17408 B, per-wave P

    const int tid   = threadIdx.x;
    const int lane  = tid & 63;
    const int wave  = tid >> 6;
    const int row16 = lane & 15;
    const int quad  = lane >> 4;

    // XCD swizzle: all 25 q-blocks of one (b,n) share blockIdx%8
    const int L = blockIdx.x;           // 0..599 (= 8 * 3 * 25)
    const int xcd = L & 7;
    const int j = L >> 3;
    const int bn = xcd * 3 + (j % 3);   // 0..23
    const int q0 = (j / 3) * 64;
    const int b = bn / NH;
    const int n = bn - b * NH;

    const float LOG2E = 1.4426950408889634f;
    const float SCALE_L2E = 0.125f * LOG2E;

    // prologue: relS[e][ql] = LOG2E * (qh[q0+ql] . table_e), 36 x 64 entries
    for (int i = tid; i < 36 * 64; i += 256) {
        const int e  = i >> 6;
        const int ql = i & 63;
        const int qg = min(q0 + ql, QS - 1);
        const float* tp;
        if (e < 8)       { int tq = qg / 196;       tp = rpt + (size_t)(tq - e + 7) * HD; }
        else if (e < 22) { int hq = (qg / 14) % 14; tp = rph + (size_t)(hq - (e - 8) + 13) * HD; }
        else             { int wq = qg % 14;        tp = rpw + (size_t)(wq - (e - 22) + 13) * HD; }
        const bf16_t* qp = qhP + ((size_t)bn * QS + qg) * 64;
        float s = 0.f;
#pragma unroll
        for (int jj = 0; jj < 8; ++jj) {
            bf16x8 a = *(const bf16x8*)(qp + jj * 8);
            floatx4 t0 = *(const floatx4*)(tp + jj * 8);
            floatx4 t1 = *(const floatx4*)(tp + jj * 8 + 4);
#pragma unroll
            for (int r = 0; r < 4; ++r) s += (float)a[r] * t0[r];
#pragma unroll
            for (int r = 0; r < 4; ++r) s += (float)a[4 + r] * t1[r];
        }
        relS[e * 68 + ql] = s * LOG2E;
    }

    // persistent Q fragments (A-layout), clamped for the last q-block
    const int qrow = q0 + wave * 16 + row16;
    const int qc   = min(qrow, QS - 1);
    const bf16_t* qp = qhP + ((size_t)bn * QS + qc) * 64 + quad * 8;
    bf16x8 aQ0 = *(const bf16x8*)(qp);
    bf16x8 aQ1 = *(const bf16x8*)(qp + 32);

    floatx4 O[4];
#pragma unroll
    for (int ct = 0; ct < 4; ++ct) O[ct] = (floatx4){0.f, 0.f, 0.f, 0.f};
    float lsum[4] = {0.f, 0.f, 0.f, 0.f};

    const bf16_t* khb = khP + (size_t)bn * KS * 64;
    const bf16_t* vTb = vT + (size_t)bn * 64 * KSP;
    const int rowb  = wave * 16 + quad * 4;   // lane's 4 local q-rows
    const int pbase = (wave * 16) * 136;

    // K staging indices: 1024 chunks of 8 bf16, 4 per thread
    const int kr[4] = { (0*256+tid) >> 3, (1*256+tid) >> 3,
                        (2*256+tid) >> 3, (3*256+tid) >> 3 };
    const int kc8 = (tid & 7) * 8;

    for (int k0 = 0; k0 < 13 * KT; k0 += KT) {
        __syncthreads();  // previous iteration's Ks readers done
        // ---- stage K tile: Ks[row][c] (stride 80), VGPR round-trip
        bf16x8 greg[4];
#pragma unroll
        for (int p = 0; p < 4; ++p) {
            const int key = min(k0 + kr[p], KS - 1);
            greg[p] = *(const bf16x8*)(khb + (size_t)key * 64 + kc8);
        }
#pragma unroll
        for (int p = 0; p < 4; ++p)
            *(bf16x8*)&Ks[kr[p] * 80 + kc8] = greg[p];
        __syncthreads();  // staging visible

        // ---- V fragments: issue now (global/L2), consume after softmax
        bf16x8 vF[16];
#pragma unroll
        for (int ct = 0; ct < 4; ++ct)
#pragma unroll
            for (int c4 = 0; c4 < 4; ++c4)
                vF[ct * 4 + c4] = *(const bf16x8*)(
                    vTb + (size_t)(ct * 16 + row16) * KSP + k0 + c4 * 32 + quad * 8);

        // ---- S = Q K^T: 8 key-tiles of 16, K-frags from LDS
        floatx4 S[8];
#pragma unroll
        for (int t = 0; t < 8; ++t) {
            const bf16_t* kp = &Ks[(t * 16 + row16) * 80 + quad * 8];
            floatx4 s = (floatx4){0.f, 0.f, 0.f, 0.f};
            s = MFMA16(aQ0, *(const bf16x8*)(kp), s);
            s = MFMA16(aQ1, *(const bf16x8*)(kp + 32), s);
            S[t] = s;
        }

        // ---- bias + exp2 (+tail mask) + P store + l accumulate
#pragma unroll
        for (int t = 0; t < 8; ++t) {
            const int key = k0 + t * 16 + row16;
            const int kt = key / 196;
            const int rem = key - kt * 196;
            const int kho = rem / 14;
            const int kwo = rem - kho * 14;
            floatx4 bias = *(const floatx4*)&relS[kt * 68 + rowb];
            bias = bias + *(const floatx4*)&relS[(8 + kho) * 68 + rowb];
            bias = bias + *(const floatx4*)&relS[(22 + kwo) * 68 + rowb];
            const bool ok = (key < KS);
#pragma unroll
            for (int r = 0; r < 4; ++r) {
                float p = __builtin_amdgcn_exp2f(S[t][r] * SCALE_L2E + bias[r]);
                p = ok ? p : 0.f;
                lsum[r] += p;
                Pl[pbase + (quad * 4 + r) * 136 + t * 16 + row16] = (bf16_t)p;
            }
        }

        // ---- O += P V  (aP via per-wave LDS round-trip; vF from registers)
        bf16x8 aP[4];
#pragma unroll
        for (int c4 = 0; c4 < 4; ++c4)
            aP[c4] = *(const bf16x8*)&Pl[pbase + row16 * 136 + c4 * 32 + quad * 8];
#pragma unroll
        for (int ct = 0; ct < 4; ++ct) {
            floatx4 o = O[ct];
#pragma unroll
            for (int c4 = 0; c4 < 4; ++c4)
                o = MFMA16(aP[c4], vF[ct * 4 + c4], o);
            O[ct] = o;
        }
    }

    // ---- epilogue: reduce l across the 16-lane key group, normalize, store
    float inv[4];
#pragma unroll
    for (int r = 0; r < 4; ++r) {
        float l = lsum[r];
        l += __shfl_xor(l, 1);
        l += __shfl_xor(l, 2);
        l += __shfl_xor(l, 4);
        l += __shfl_xor(l, 8);
        inv[r] = 1.f / l;
    }
#pragma unroll
    for (int ct = 0; ct < 4; ++ct) {
        const int c = n * HD + ct * 16 + row16;
#pragma unroll
        for (int r = 0; r < 4; ++r) {
            const int qr = q0 + wave * 16 + quad * 4 + r;
            if (qr < QS)
                ao[(size_t)(b * QS + qr) * DIM + c] = (bf16_t)(O[ct][r] * inv[r]);
        }
    }
}

// ---------------------------------------------------------------------------
// O-projection GEMM: Y(f32) = X(bf16) @ Wo^T + bo. Tile 64x64, BK=64.
// ---------------------------------------------------------------------------
__global__ __launch_bounds__(256) void gemm_o(
    const bf16_t* __restrict__ X, const bf16_t* __restrict__ W,
    const float* __restrict__ bias, float* __restrict__ Y)
{
    __shared__ __align__(16) bf16_t As[64 * 64];   // 8 KB
    __shared__ __align__(16) bf16_t Bs[64 * 64];   // 8 KB

    const int tid   = threadIdx.x;
    const int lane  = tid & 63;
    const int wave  = tid >> 6;
    const int row16 = lane & 15;
    const int quad  = lane >> 4;
    const int m0 = blockIdx.x * 64;
    const int n0 = blockIdx.y * 64;

    floatx4 acc[4];
#pragma unroll
    for (int nt = 0; nt < 4; ++nt) acc[nt] = (floatx4){0.f, 0.f, 0.f, 0.f};

    for (int k0 = 0; k0 < DIM; k0 += 64) {
        __syncthreads();
#pragma unroll
        for (int pp = 0; pp < 2; ++pp) {
            const int c = pp * 256 + tid;
            const int row = c >> 3;
            const int g = (c & 7) ^ (row & 7);
            async16(X + (size_t)(m0 + row) * DIM + k0 + g * 8, As + c * 8);
            async16(W + (size_t)(n0 + row) * DIM + k0 + g * 8, Bs + c * 8);
        }
        __syncthreads();

#pragma unroll
        for (int h = 0; h < 2; ++h) {
            const int gl = h * 4 + quad;
            const int rowA = wave * 16 + row16;
            bf16x8 aF = *(const bf16x8*)&As[rowA * 64 + (gl ^ (row16 & 7)) * 8];
#pragma unroll
            for (int nt = 0; nt < 4; ++nt) {
                const int rowB = nt * 16 + row16;
                bf16x8 bF = *(const bf16x8*)&Bs[rowB * 64 + (gl ^ (row16 & 7)) * 8];
                acc[nt] = MFMA16(aF, bF, acc[nt]);
            }
        }
    }

#pragma unroll
    for (int nt = 0; nt < 4; ++nt) {
        const int col = n0 + nt * 16 + row16;
        const float bv = bias[col];
#pragma unroll
        for (int r = 0; r < 4; ++r) {
            const int row = m0 + wave * 16 + quad * 4 + r;
            Y[(size_t)row * DIM + col] = acc[nt][r] + bv;
        }
    }
}

// ---------------------------------------------------------------------------
extern "C" void kernel_launch(void* const* d_in, const int* in_sizes, int n_in,
                              void* d_out, int out_size, void* d_ws, size_t ws_size,
                              hipStream_t stream) {
    const float* q   = (const float*)d_in[0];
    const float* k   = (const float*)d_in[1];
    const float* Wq  = (const float*)d_in[2];
    const float* bq  = (const float*)d_in[3];
    const float* Wk  = (const float*)d_in[4];
    const float* bk  = (const float*)d_in[5];
    const float* Wv  = (const float*)d_in[6];
    const float* bv  = (const float*)d_in[7];
    const float* Wo  = (const float*)d_in[8];
    const float* bo  = (const float*)d_in[9];
    const float* rpt = (const float*)d_in[10];
    const float* rph = (const float*)d_in[11];
    const float* rpw = (const float*)d_in[12];

    // workspace (~23.4 MB): qhP, khP, vT (padded), ao, Wb
    bf16_t* qhP = (bf16_t*)d_ws;
    bf16_t* khP = qhP + (size_t)MROWS * DIM;
    bf16_t* vT  = khP + (size_t)MROWS * DIM;
    bf16_t* ao  = vT  + (size_t)BB * NH * HD * KSP;
    bf16_t* Wb  = ao  + (size_t)MROWS * DIM;      // [Wq|Wk|Wv|Wo]

    cvt_w<<<(4 * (DIM * DIM / 4) + 255) / 256, 256, 0, stream>>>(Wq, Wk, Wv, Wo, Wb);

    gemm_qkv<<<dim3(25, 36), 256, 0, stream>>>(q, k, Wb, bq, bk, bv, qhP, khP, vT);

    attn_fused<<<dim3(8 * 3 * 25), 256, 0, stream>>>(
        qhP, khP, vT, rpt, rph, rpw, ao);

    gemm_o<<<dim3(MROWS / 64, DIM / 64), 256, 0, stream>>>(
        ao, Wb + (size_t)3 * DIM * DIM, bo, (float*)d_out);
}